// Round 8
// baseline (513.288 us; speedup 1.0000x reference)
//
#include <hip/hip_runtime.h>

#define NELL 9
#define CCH  128
#define DB   3
#define P3A  5
#define P2A  3
#define P1A  1
#define P3B  5
#define P2B  2
#define P1B  1
#define NT3  165
#define NT2  45
#define RW3  20                       // T3 row width: 5 (block0) + 15 (block1 d-major)
#define RW2  9                        // T2 row width: 3 + 6
#define RW1  4                        // T1 row width: 1 + 3
#define OFF2 (NT3 * RW3)              // 3300
#define OFF1 (OFF2 + NT2 * RW2)       // 3705
#define UT_FLOATS (OFF1 + NELL * RW1) // 3741 floats = 15 KB

// ---------------------------------------------------------------------------
// Prep: c-independent symmetric-collapsed U' table (mult folded in), 15 KB.
//   triples t<165: row[p]=mult*U3a[ijk,p]; row[5+5d+p]=mult*U3b[d,ijk,p]
//   pairs:         row[p]=mult*U2a[ij,p];  row[3+2d+p]=mult*U2b[d,ij,p]
//   singles:       row[0]=U1a[i];          row[1+d]=U1b[d,i]
// ---------------------------------------------------------------------------
__global__ void sc_prep(const float* __restrict__ U3a, const float* __restrict__ U2a,
                        const float* __restrict__ U1a, const float* __restrict__ U3b,
                        const float* __restrict__ U2b, const float* __restrict__ U1b,
                        float* __restrict__ ut)
{
    const int t = threadIdx.x;
    if (t < NT3) {
        int idx = t, i = 0, j = 0, k = 0;
        bool done = false;
        for (i = 0; i < NELL && !done; i++)
            for (j = i; j < NELL && !done; j++)
                for (k = j; k < NELL; k++) {
                    if (idx == 0) { done = true; break; }
                    idx--;
                }
        i--; j--;  // undo post-increment of aborted loops
        const float mult = (i == k) ? 1.f : ((i == j || j == k) ? 3.f : 6.f);
        const int ijk = (i * 9 + j) * 9 + k;
        float* r = ut + t * RW3;
        for (int p = 0; p < P3A; p++) r[p] = mult * U3a[ijk * P3A + p];
        for (int d = 0; d < DB; d++)
            for (int p = 0; p < P3B; p++)
                r[P3A + d * P3B + p] = mult * U3b[(d * 729 + ijk) * P3B + p];
    } else if (t < NT3 + NT2) {
        int idx = t - NT3, i = 0, j = 0;
        bool done = false;
        for (i = 0; i < NELL && !done; i++)
            for (j = i; j < NELL; j++) {
                if (idx == 0) { done = true; break; }
                idx--;
            }
        i--;
        const float mult = (i == j) ? 1.f : 2.f;
        const int ij = i * 9 + j;
        float* r = ut + OFF2 + (t - NT3) * RW2;
        for (int p = 0; p < P2A; p++) r[p] = mult * U2a[ij * P2A + p];
        for (int d = 0; d < DB; d++)
            for (int p = 0; p < P2B; p++)
                r[P2A + d * P2B + p] = mult * U2b[(d * 81 + ij) * P2B + p];
    } else if (t < NT3 + NT2 + NELL) {
        const int i = t - NT3 - NT2;
        float* r = ut + OFF1 + i * RW1;
        r[0] = U1a[i];
        for (int d = 0; d < DB; d++) r[1 + d] = U1b[d * 9 + i];
    }
}

// ---------------------------------------------------------------------------
// Main: one thread per (b,c). U' table broadcast from LDS (c-independent),
// 33 register accumulators, W applied per-e at the end (17 coalesced loads).
// i,j unrolled (register xv); k runtime reads per-lane LDS mirror xs.
// ---------------------------------------------------------------------------
__global__ __launch_bounds__(CCH)
void sc_main(const float* __restrict__ x, const float* __restrict__ y, int E,
             const float* __restrict__ ut,
             const float* __restrict__ W3a, const float* __restrict__ W2a,
             const float* __restrict__ W1a, const float* __restrict__ W3b,
             const float* __restrict__ W2b, const float* __restrict__ W1b,
             float* __restrict__ out)
{
    __shared__ float t3s[NT3 * RW3];
    __shared__ float t2s[NT2 * RW2];
    __shared__ float t1s[NELL * RW1];
    __shared__ float xs[CCH * NELL];

    const int c = threadIdx.x;
    const int b = blockIdx.x;

    for (int i = c; i < NT3 * RW3; i += CCH) t3s[i] = ut[i];
    for (int i = c; i < NT2 * RW2; i += CCH) t2s[i] = ut[OFF2 + i];
    if (c < NELL * RW1) t1s[c] = ut[OFF1 + c];

    float xv[NELL];
    const float* xp = x + (b * CCH + c) * NELL;
#pragma unroll
    for (int i = 0; i < NELL; i++) { xv[i] = xp[i]; xs[c * NELL + i] = xv[i]; }
    __syncthreads();

    int e = 0;  // wave-uniform one-hot scan
    for (int q = 0; q < E; q++)
        if (y[b * E + q] > 0.5f) e = q;

    float a3[RW3] = {};
    float a2[RW2] = {};
    float a1[RW1] = {};

    int t3 = 0;
    const float* xrow = &xs[c * NELL];
#pragma unroll
    for (int i = 0; i < NELL; i++) {
#pragma unroll
        for (int j = i; j < NELL; j++) {
            const float pij = xv[i] * xv[j];
            const int p2 = i * NELL - (i * (i - 1)) / 2 + (j - i);  // compile-time
            const float* r2 = &t2s[p2 * RW2];
#pragma unroll
            for (int q = 0; q < RW2; q++) a2[q] = fmaf(r2[q], pij, a2[q]);
            for (int k = j; k < NELL; k++) {  // runtime: xv via LDS mirror
                const float m = pij * xrow[k];
                const float4* r3 = (const float4*)&t3s[t3 * RW3];
                const float4 w0 = r3[0], w1 = r3[1], w2 = r3[2], w3 = r3[3], w4 = r3[4];
                a3[0]  = fmaf(w0.x, m, a3[0]);
                a3[1]  = fmaf(w0.y, m, a3[1]);
                a3[2]  = fmaf(w0.z, m, a3[2]);
                a3[3]  = fmaf(w0.w, m, a3[3]);
                a3[4]  = fmaf(w1.x, m, a3[4]);
                a3[5]  = fmaf(w1.y, m, a3[5]);
                a3[6]  = fmaf(w1.z, m, a3[6]);
                a3[7]  = fmaf(w1.w, m, a3[7]);
                a3[8]  = fmaf(w2.x, m, a3[8]);
                a3[9]  = fmaf(w2.y, m, a3[9]);
                a3[10] = fmaf(w2.z, m, a3[10]);
                a3[11] = fmaf(w2.w, m, a3[11]);
                a3[12] = fmaf(w3.x, m, a3[12]);
                a3[13] = fmaf(w3.y, m, a3[13]);
                a3[14] = fmaf(w3.z, m, a3[14]);
                a3[15] = fmaf(w3.w, m, a3[15]);
                a3[16] = fmaf(w4.x, m, a3[16]);
                a3[17] = fmaf(w4.y, m, a3[17]);
                a3[18] = fmaf(w4.z, m, a3[18]);
                a3[19] = fmaf(w4.w, m, a3[19]);
                t3++;
            }
        }
    }
#pragma unroll
    for (int i = 0; i < NELL; i++) {
#pragma unroll
        for (int q = 0; q < RW1; q++) a1[q] = fmaf(t1s[i * RW1 + q], xv[i], a1[q]);
    }

    // epilogue: per-element weights (coalesced across c)
    float o0 = 0.f;
#pragma unroll
    for (int p = 0; p < P3A; p++) o0 = fmaf(W3a[(e * P3A + p) * CCH + c], a3[p], o0);
#pragma unroll
    for (int p = 0; p < P2A; p++) o0 = fmaf(W2a[(e * P2A + p) * CCH + c], a2[p], o0);
    o0 = fmaf(W1a[e * CCH + c], a1[0], o0);

    float o1[DB] = {};
#pragma unroll
    for (int p = 0; p < P3B; p++) {
        const float w = W3b[(e * P3B + p) * CCH + c];
#pragma unroll
        for (int d = 0; d < DB; d++) o1[d] = fmaf(w, a3[P3A + d * P3B + p], o1[d]);
    }
#pragma unroll
    for (int p = 0; p < P2B; p++) {
        const float w = W2b[(e * P2B + p) * CCH + c];
#pragma unroll
        for (int d = 0; d < DB; d++) o1[d] = fmaf(w, a2[P2A + d * P2B + p], o1[d]);
    }
    {
        const float w = W1b[e * CCH + c];
#pragma unroll
        for (int d = 0; d < DB; d++) o1[d] = fmaf(w, a1[1 + d], o1[d]);
    }

    float* op = out + b * (CCH * 4);  // [128 (block0) | 384 (block1, c*3+d)]
    op[c] = o0;
    op[CCH + c * DB + 0] = o1[0];
    op[CCH + c * DB + 1] = o1[1];
    op[CCH + c * DB + 2] = o1[2];
}

// ---------------------------------------------------------------------------
// Fallback: round-5 proven direct kernel (used only if ws < 15 KB).
// ---------------------------------------------------------------------------
__global__ __launch_bounds__(CCH)
void sc_direct(const float* __restrict__ x, const float* __restrict__ y, int E,
               const float* __restrict__ U3a, const float* __restrict__ U2a, const float* __restrict__ U1a,
               const float* __restrict__ U3b, const float* __restrict__ U2b, const float* __restrict__ U1b,
               const float* __restrict__ W3a, const float* __restrict__ W2a, const float* __restrict__ W1a,
               const float* __restrict__ W3b, const float* __restrict__ W2b, const float* __restrict__ W1b,
               float* __restrict__ out)
{
    const int c = threadIdx.x;
    const int b = blockIdx.x;

    float xv[NELL];
#pragma unroll
    for (int i = 0; i < NELL; i++) xv[i] = x[(b * CCH + c) * NELL + i];

    int e = 0;
    for (int q = 0; q < E; q++)
        if (y[b * E + q] > 0.5f) e = q;

    float t3a[P3A] = {}, t3b[DB * P3B] = {};
    float t2a[P2A] = {}, t2b[DB * P2B] = {};
    float t1a = 0.f, t1b[DB] = {};

    for (int i = 0; i < NELL; i++) {
        const float xi = xv[i];
        for (int j = 0; j < NELL; j++) {
            const float xij = xi * xv[j];
            const int ij = i * 9 + j;
#pragma unroll
            for (int p = 0; p < P2A; p++)
                t2a[p] = fmaf(U2a[ij * P2A + p], xij, t2a[p]);
#pragma unroll
            for (int d = 0; d < DB; d++)
#pragma unroll
                for (int p = 0; p < P2B; p++)
                    t2b[d * P2B + p] = fmaf(U2b[(d * 81 + ij) * P2B + p], xij, t2b[d * P2B + p]);
            for (int k = 0; k < NELL; k++) {
                const float m = xij * xv[k];
                const int ijk = ij * 9 + k;
#pragma unroll
                for (int p = 0; p < P3A; p++)
                    t3a[p] = fmaf(U3a[ijk * P3A + p], m, t3a[p]);
#pragma unroll
                for (int d = 0; d < DB; d++)
#pragma unroll
                    for (int p = 0; p < P3B; p++)
                        t3b[d * P3B + p] = fmaf(U3b[(d * 729 + ijk) * P3B + p], m, t3b[d * P3B + p]);
            }
        }
    }
#pragma unroll
    for (int i = 0; i < NELL; i++) {
        t1a = fmaf(U1a[i], xv[i], t1a);
#pragma unroll
        for (int d = 0; d < DB; d++)
            t1b[d] = fmaf(U1b[d * 9 + i], xv[i], t1b[d]);
    }

    float o0 = 0.f;
#pragma unroll
    for (int p = 0; p < P3A; p++) o0 = fmaf(W3a[(e * P3A + p) * CCH + c], t3a[p], o0);
#pragma unroll
    for (int p = 0; p < P2A; p++) o0 = fmaf(W2a[(e * P2A + p) * CCH + c], t2a[p], o0);
    o0 = fmaf(W1a[e * CCH + c], t1a, o0);

    float o1[DB] = {};
#pragma unroll
    for (int p = 0; p < P3B; p++) {
        const float w = W3b[(e * P3B + p) * CCH + c];
#pragma unroll
        for (int d = 0; d < DB; d++) o1[d] = fmaf(w, t3b[d * P3B + p], o1[d]);
    }
#pragma unroll
    for (int p = 0; p < P2B; p++) {
        const float w = W2b[(e * P2B + p) * CCH + c];
#pragma unroll
        for (int d = 0; d < DB; d++) o1[d] = fmaf(w, t2b[d * P2B + p], o1[d]);
    }
    {
        const float w = W1b[e * CCH + c];
#pragma unroll
        for (int d = 0; d < DB; d++) o1[d] = fmaf(w, t1b[d], o1[d]);
    }

    float* op = out + b * (CCH * 4);
    op[c] = o0;
#pragma unroll
    for (int d = 0; d < DB; d++) op[CCH + c * DB + d] = o1[d];
}

extern "C" void kernel_launch(void* const* d_in, const int* in_sizes, int n_in,
                              void* d_out, int out_size, void* d_ws, size_t ws_size,
                              hipStream_t stream)
{
    // ---- order-agnostic classification by element counts (proven in r5-r7) ----
    int ix = 0;
    for (int i = 1; i < n_in; i++)
        if (in_sizes[i] > in_sizes[ix]) ix = i;
    int B = in_sizes[ix] / (CCH * NELL);
    bool ok = (n_in == 14) && (B > 0) && (in_sizes[ix] == B * CCH * NELL);

    int iy = -1, E = 0;
    if (ok) {
        for (int i = 0; i < n_in; i++) {
            if (i == ix) continue;
            if (in_sizes[i] % B == 0) {
                int Ec = in_sizes[i] / B;
                if (Ec >= 2 && Ec <= 1024) {
                    if (iy < 0) { iy = i; E = Ec; } else { ok = false; }
                }
            }
        }
        if (iy < 0) ok = false;
    }

    int iU1a = -1, iU2a = -1, iU3a = -1, iU1b = -1, iU2b = -1, iU3b = -1;
    int iW1a = -1, iW1b = -1, iW2a = -1, iW2b = -1, iW3a = -1, iW3b = -1;
    if (ok) {
        for (int i = 0; i < n_in && ok; i++) {
            if (i == ix || i == iy) continue;
            int s = in_sizes[i];
            if      (s == 9 * P1A)        { if (iU1a < 0) iU1a = i; else ok = false; }
            else if (s == 81 * P2A)       { if (iU2a < 0) iU2a = i; else ok = false; }
            else if (s == 729 * P3A)      { if (iU3a < 0) iU3a = i; else ok = false; }
            else if (s == 27 * P1B)       { if (iU1b < 0) iU1b = i; else ok = false; }
            else if (s == 243 * P2B)      { if (iU2b < 0) iU2b = i; else ok = false; }
            else if (s == 2187 * P3B)     { if (iU3b < 0) iU3b = i; else ok = false; }
            else if (s == E * P1A * CCH)  { if (iW1a < 0) iW1a = i; else if (iW1b < 0) iW1b = i; else ok = false; }
            else if (s == E * P2A * CCH)  { if (iW2a < 0) iW2a = i; else ok = false; }
            else if (s == E * P2B * CCH)  { if (iW2b < 0) iW2b = i; else ok = false; }
            else if (s == E * P3A * CCH)  { if (iW3a < 0) iW3a = i; else if (iW3b < 0) iW3b = i; else ok = false; }
            else ok = false;
        }
        if (iU1a < 0 || iU2a < 0 || iU3a < 0 || iU1b < 0 || iU2b < 0 || iU3b < 0 ||
            iW1a < 0 || iW1b < 0 || iW2a < 0 || iW2b < 0 || iW3a < 0 || iW3b < 0)
            ok = false;
    }

    if (!ok) {
        // dict-order fallback
        ix = 0; iy = 1;
        B = in_sizes[0] / (CCH * NELL);
        E = (B > 0) ? in_sizes[1] / B : 1;
        iU1a = 2;  iW1a = 3;  iU2a = 4;  iW2a = 5;  iU3a = 6;  iW3a = 7;
        iU1b = 8;  iW1b = 9;  iU2b = 10; iW2b = 11; iU3b = 12; iW3b = 13;
    }

    if (ws_size >= (size_t)UT_FLOATS * sizeof(float)) {
        hipLaunchKernelGGL(sc_prep, dim3(1), dim3(256), 0, stream,
                           (const float*)d_in[iU3a], (const float*)d_in[iU2a], (const float*)d_in[iU1a],
                           (const float*)d_in[iU3b], (const float*)d_in[iU2b], (const float*)d_in[iU1b],
                           (float*)d_ws);
        hipLaunchKernelGGL(sc_main, dim3(B), dim3(CCH), 0, stream,
                           (const float*)d_in[ix], (const float*)d_in[iy], E,
                           (const float*)d_ws,
                           (const float*)d_in[iW3a], (const float*)d_in[iW2a], (const float*)d_in[iW1a],
                           (const float*)d_in[iW3b], (const float*)d_in[iW2b], (const float*)d_in[iW1b],
                           (float*)d_out);
    } else {
        hipLaunchKernelGGL(sc_direct, dim3(B), dim3(CCH), 0, stream,
                           (const float*)d_in[ix], (const float*)d_in[iy], E,
                           (const float*)d_in[iU3a], (const float*)d_in[iU2a], (const float*)d_in[iU1a],
                           (const float*)d_in[iU3b], (const float*)d_in[iU2b], (const float*)d_in[iU1b],
                           (const float*)d_in[iW3a], (const float*)d_in[iW2a], (const float*)d_in[iW1a],
                           (const float*)d_in[iW3b], (const float*)d_in[iW2b], (const float*)d_in[iW1b],
                           (float*)d_out);
    }
}

// Round 9
// 66.295 us; speedup vs baseline: 7.7425x; 7.7425x over previous
//
#include <hip/hip_runtime.h>

#define NELL 9
#define CCH  128
#define DB   3
#define P3A  5
#define P2A  3
#define P1A  1
#define P3B  5
#define P2B  2
#define P1B  1
#define NT3  165
#define NT2  45
#define TTOT (NT3 + NT2 + NELL)   // 219 monomials (sorted triples, pairs, singles)
#define GROUP 2                   // same-e rows per block in grouped main

// ---------------------------------------------------------------------------
// Grouping: perm[slot] = batch index, sorted by element type e (stable enough;
// output is independent of intra-group order: each b processed once, fixed FMA
// order per row).
// ---------------------------------------------------------------------------
__global__ void sc_group(const float* __restrict__ y, int B, int E,
                         int* __restrict__ perm)
{
    __shared__ int cnt[1024];
    __shared__ int off[1024];
    for (int i = threadIdx.x; i < E; i += blockDim.x) cnt[i] = 0;
    __syncthreads();
    for (int b = threadIdx.x; b < B; b += blockDim.x) {
        int e = 0;
        for (int q = 0; q < E; q++) if (y[b * E + q] > 0.5f) e = q;
        atomicAdd(&cnt[e], 1);
    }
    __syncthreads();
    if (threadIdx.x == 0) {
        int s = 0;
        for (int e = 0; e < E; e++) { off[e] = s; s += cnt[e]; }
    }
    __syncthreads();
    for (int i = threadIdx.x; i < E; i += blockDim.x) cnt[i] = 0;
    __syncthreads();
    for (int b = threadIdx.x; b < B; b += blockDim.x) {
        int e = 0;
        for (int q = 0; q < E; q++) if (y[b * E + q] > 0.5f) e = q;
        int r = atomicAdd(&cnt[e], 1);
        perm[off[e] + r] = b;
    }
}

// ---------------------------------------------------------------------------
// Prep (r7-proven): fused coefficient table, layout [e][t][c] float4 over d:
//   tab4[(e*TTOT + t)*CCH + c] = mult_t * { sum_p U_nu[d,t,p] * W_nu[e,p,c] }
// ---------------------------------------------------------------------------
__global__ __launch_bounds__(CCH)
void sc_prep(const float* __restrict__ U3a, const float* __restrict__ U2a,
             const float* __restrict__ U1a, const float* __restrict__ U3b,
             const float* __restrict__ U2b, const float* __restrict__ U1b,
             const float* __restrict__ W3a, const float* __restrict__ W2a,
             const float* __restrict__ W1a, const float* __restrict__ W3b,
             const float* __restrict__ W2b, const float* __restrict__ W1b,
             float* __restrict__ tab)
{
    const int bt = blockIdx.x;
    const int e = bt / TTOT, t = bt % TTOT;
    const int c = threadIdx.x;

    float v[4] = {0.f, 0.f, 0.f, 0.f};

    if (t < NT3) {
        int idx = t, i = 0, j = 0, k = 0;
        bool done = false;
        for (i = 0; i < NELL && !done; i++)
            for (j = i; j < NELL && !done; j++)
                for (k = j; k < NELL; k++) {
                    if (idx == 0) { done = true; break; }
                    idx--;
                }
        i--; j--;
        const float mult = (i == k) ? 1.f : ((i == j || j == k) ? 3.f : 6.f);
        const int ijk = (i * 9 + j) * 9 + k;
        for (int p = 0; p < P3A; p++)
            v[0] += U3a[ijk * P3A + p] * W3a[(e * P3A + p) * CCH + c];
        for (int d = 0; d < DB; d++)
            for (int p = 0; p < P3B; p++)
                v[1 + d] += U3b[(d * 729 + ijk) * P3B + p] * W3b[(e * P3B + p) * CCH + c];
        for (int d = 0; d < 4; d++) v[d] *= mult;
    } else if (t < NT3 + NT2) {
        int idx = t - NT3, i = 0, j = 0;
        bool done = false;
        for (i = 0; i < NELL && !done; i++)
            for (j = i; j < NELL; j++) {
                if (idx == 0) { done = true; break; }
                idx--;
            }
        i--;
        const float mult = (i == j) ? 1.f : 2.f;
        const int ij = i * 9 + j;
        for (int p = 0; p < P2A; p++)
            v[0] += U2a[ij * P2A + p] * W2a[(e * P2A + p) * CCH + c];
        for (int d = 0; d < DB; d++)
            for (int p = 0; p < P2B; p++)
                v[1 + d] += U2b[(d * 81 + ij) * P2B + p] * W2b[(e * P2B + p) * CCH + c];
        for (int d = 0; d < 4; d++) v[d] *= mult;
    } else {
        const int i = t - NT3 - NT2;
        v[0] = U1a[i] * W1a[e * CCH + c];
        for (int d = 0; d < DB; d++)
            v[1 + d] = U1b[d * 9 + i] * W1b[e * CCH + c];
    }

    ((float4*)tab)[(size_t)bt * CCH + c] = make_float4(v[0], v[1], v[2], v[3]);
}

// ---------------------------------------------------------------------------
// Contraction core for 2 rows; SAME=true shares the table load (same e).
// t-order and FMA order identical to r7 per row (bit-identical results).
// ---------------------------------------------------------------------------
template <bool SAME>
__device__ __forceinline__ void contract2(const float4* __restrict__ cp0,
                                          const float4* __restrict__ cp1,
                                          const float* xv0, const float* xv1,
                                          float4& A0, float4& A1)
{
    int t = 0;
#pragma unroll
    for (int i = 0; i < NELL; i++) {
#pragma unroll
        for (int j = i; j < NELL; j++) {
            const float p0 = xv0[i] * xv0[j];
            const float p1 = xv1[i] * xv1[j];
#pragma unroll
            for (int k = j; k < NELL; k++) {
                const float m0 = p0 * xv0[k];
                const float m1 = p1 * xv1[k];
                const float4 w0 = cp0[t * CCH];
                const float4 w1 = SAME ? w0 : cp1[t * CCH];
                A0.x = fmaf(w0.x, m0, A0.x);
                A0.y = fmaf(w0.y, m0, A0.y);
                A0.z = fmaf(w0.z, m0, A0.z);
                A0.w = fmaf(w0.w, m0, A0.w);
                A1.x = fmaf(w1.x, m1, A1.x);
                A1.y = fmaf(w1.y, m1, A1.y);
                A1.z = fmaf(w1.z, m1, A1.z);
                A1.w = fmaf(w1.w, m1, A1.w);
                t++;
            }
        }
    }
#pragma unroll
    for (int i = 0; i < NELL; i++) {
#pragma unroll
        for (int j = i; j < NELL; j++) {
            const float p0 = xv0[i] * xv0[j];
            const float p1 = xv1[i] * xv1[j];
            const float4 w0 = cp0[t * CCH];
            const float4 w1 = SAME ? w0 : cp1[t * CCH];
            A0.x = fmaf(w0.x, p0, A0.x);
            A0.y = fmaf(w0.y, p0, A0.y);
            A0.z = fmaf(w0.z, p0, A0.z);
            A0.w = fmaf(w0.w, p0, A0.w);
            A1.x = fmaf(w1.x, p1, A1.x);
            A1.y = fmaf(w1.y, p1, A1.y);
            A1.z = fmaf(w1.z, p1, A1.z);
            A1.w = fmaf(w1.w, p1, A1.w);
            t++;
        }
    }
#pragma unroll
    for (int i = 0; i < NELL; i++) {
        const float4 w0 = cp0[t * CCH];
        const float4 w1 = SAME ? w0 : cp1[t * CCH];
        A0.x = fmaf(w0.x, xv0[i], A0.x);
        A0.y = fmaf(w0.y, xv0[i], A0.y);
        A0.z = fmaf(w0.z, xv0[i], A0.z);
        A0.w = fmaf(w0.w, xv0[i], A0.w);
        A1.x = fmaf(w1.x, xv1[i], A1.x);
        A1.y = fmaf(w1.y, xv1[i], A1.y);
        A1.z = fmaf(w1.z, xv1[i], A1.z);
        A1.w = fmaf(w1.w, xv1[i], A1.w);
        t++;
    }
}

// ---------------------------------------------------------------------------
// Grouped main: block handles GROUP=2 perm-adjacent rows (same e except at
// <=E-1 boundary blocks). One table load feeds both rows.
// ---------------------------------------------------------------------------
__global__ __launch_bounds__(CCH)
void sc_main2(const float* __restrict__ x, const float* __restrict__ y, int E, int B,
              const int* __restrict__ perm, const float* __restrict__ tab,
              float* __restrict__ out)
{
    const int c = threadIdx.x;
    const int r0 = blockIdx.x * GROUP;
    const int r1 = r0 + 1;
    const bool two = (r1 < B);

    const int b0 = perm[r0];
    const int b1 = two ? perm[r1] : b0;

    int e0 = 0, e1 = 0;
    for (int q = 0; q < E; q++) if (y[b0 * E + q] > 0.5f) e0 = q;
    for (int q = 0; q < E; q++) if (y[b1 * E + q] > 0.5f) e1 = q;

    float xv0[NELL], xv1[NELL];
    const float* xp0 = x + (b0 * CCH + c) * NELL;
    const float* xp1 = x + (b1 * CCH + c) * NELL;
#pragma unroll
    for (int i = 0; i < NELL; i++) { xv0[i] = xp0[i]; xv1[i] = xp1[i]; }

    const float4* cp0 = (const float4*)tab + (size_t)e0 * TTOT * CCH + c;
    const float4* cp1 = (const float4*)tab + (size_t)e1 * TTOT * CCH + c;

    float4 A0 = make_float4(0.f, 0.f, 0.f, 0.f);
    float4 A1 = make_float4(0.f, 0.f, 0.f, 0.f);

    if (e0 == e1) contract2<true>(cp0, cp1, xv0, xv1, A0, A1);
    else          contract2<false>(cp0, cp1, xv0, xv1, A0, A1);

    float* op0 = out + b0 * (CCH * 4);
    op0[c] = A0.x;
    op0[CCH + c * DB + 0] = A0.y;
    op0[CCH + c * DB + 1] = A0.z;
    op0[CCH + c * DB + 2] = A0.w;
    if (two) {
        float* op1 = out + b1 * (CCH * 4);
        op1[c] = A1.x;
        op1[CCH + c * DB + 0] = A1.y;
        op1[CCH + c * DB + 1] = A1.z;
        op1[CCH + c * DB + 2] = A1.w;
    }
}

// ---------------------------------------------------------------------------
// r7 fallback main (no grouping): one row per block.
// ---------------------------------------------------------------------------
__global__ __launch_bounds__(CCH)
void sc_main1(const float* __restrict__ x, const float* __restrict__ y, int E,
              const float* __restrict__ tab, float* __restrict__ out)
{
    const int c = threadIdx.x;
    const int b = blockIdx.x;

    float xv[NELL];
    const float* xp = x + (b * CCH + c) * NELL;
#pragma unroll
    for (int i = 0; i < NELL; i++) xv[i] = xp[i];

    int e = 0;
    for (int q = 0; q < E; q++) if (y[b * E + q] > 0.5f) e = q;

    const float4* cp = (const float4*)tab + (size_t)e * TTOT * CCH + c;
    float4 A = make_float4(0.f, 0.f, 0.f, 0.f);
    int t = 0;
#pragma unroll
    for (int i = 0; i < NELL; i++)
#pragma unroll
        for (int j = i; j < NELL; j++) {
            const float pij = xv[i] * xv[j];
#pragma unroll
            for (int k = j; k < NELL; k++) {
                const float m = pij * xv[k];
                const float4 w = cp[(t++) * CCH];
                A.x = fmaf(w.x, m, A.x);
                A.y = fmaf(w.y, m, A.y);
                A.z = fmaf(w.z, m, A.z);
                A.w = fmaf(w.w, m, A.w);
            }
        }
#pragma unroll
    for (int i = 0; i < NELL; i++)
#pragma unroll
        for (int j = i; j < NELL; j++) {
            const float pij = xv[i] * xv[j];
            const float4 w = cp[(t++) * CCH];
            A.x = fmaf(w.x, pij, A.x);
            A.y = fmaf(w.y, pij, A.y);
            A.z = fmaf(w.z, pij, A.z);
            A.w = fmaf(w.w, pij, A.w);
        }
#pragma unroll
    for (int i = 0; i < NELL; i++) {
        const float4 w = cp[(t++) * CCH];
        A.x = fmaf(w.x, xv[i], A.x);
        A.y = fmaf(w.y, xv[i], A.y);
        A.z = fmaf(w.z, xv[i], A.z);
        A.w = fmaf(w.w, xv[i], A.w);
    }

    float* op = out + b * (CCH * 4);
    op[c] = A.x;
    op[CCH + c * DB + 0] = A.y;
    op[CCH + c * DB + 1] = A.z;
    op[CCH + c * DB + 2] = A.w;
}

// ---------------------------------------------------------------------------
// Last-resort fallback (no ws): r5 direct kernel.
// ---------------------------------------------------------------------------
__global__ __launch_bounds__(CCH)
void sc_direct(const float* __restrict__ x, const float* __restrict__ y, int E,
               const float* __restrict__ U3a, const float* __restrict__ U2a, const float* __restrict__ U1a,
               const float* __restrict__ U3b, const float* __restrict__ U2b, const float* __restrict__ U1b,
               const float* __restrict__ W3a, const float* __restrict__ W2a, const float* __restrict__ W1a,
               const float* __restrict__ W3b, const float* __restrict__ W2b, const float* __restrict__ W1b,
               float* __restrict__ out)
{
    const int c = threadIdx.x;
    const int b = blockIdx.x;

    float xv[NELL];
#pragma unroll
    for (int i = 0; i < NELL; i++) xv[i] = x[(b * CCH + c) * NELL + i];

    int e = 0;
    for (int q = 0; q < E; q++) if (y[b * E + q] > 0.5f) e = q;

    float t3a[P3A] = {}, t3b[DB * P3B] = {};
    float t2a[P2A] = {}, t2b[DB * P2B] = {};
    float t1a = 0.f, t1b[DB] = {};

    for (int i = 0; i < NELL; i++) {
        const float xi = xv[i];
        for (int j = 0; j < NELL; j++) {
            const float xij = xi * xv[j];
            const int ij = i * 9 + j;
#pragma unroll
            for (int p = 0; p < P2A; p++)
                t2a[p] = fmaf(U2a[ij * P2A + p], xij, t2a[p]);
#pragma unroll
            for (int d = 0; d < DB; d++)
#pragma unroll
                for (int p = 0; p < P2B; p++)
                    t2b[d * P2B + p] = fmaf(U2b[(d * 81 + ij) * P2B + p], xij, t2b[d * P2B + p]);
            for (int k = 0; k < NELL; k++) {
                const float m = xij * xv[k];
                const int ijk = ij * 9 + k;
#pragma unroll
                for (int p = 0; p < P3A; p++)
                    t3a[p] = fmaf(U3a[ijk * P3A + p], m, t3a[p]);
#pragma unroll
                for (int d = 0; d < DB; d++)
#pragma unroll
                    for (int p = 0; p < P3B; p++)
                        t3b[d * P3B + p] = fmaf(U3b[(d * 729 + ijk) * P3B + p], m, t3b[d * P3B + p]);
            }
        }
    }
#pragma unroll
    for (int i = 0; i < NELL; i++) {
        t1a = fmaf(U1a[i], xv[i], t1a);
#pragma unroll
        for (int d = 0; d < DB; d++)
            t1b[d] = fmaf(U1b[d * 9 + i], xv[i], t1b[d]);
    }

    float o0 = 0.f;
#pragma unroll
    for (int p = 0; p < P3A; p++) o0 = fmaf(W3a[(e * P3A + p) * CCH + c], t3a[p], o0);
#pragma unroll
    for (int p = 0; p < P2A; p++) o0 = fmaf(W2a[(e * P2A + p) * CCH + c], t2a[p], o0);
    o0 = fmaf(W1a[e * CCH + c], t1a, o0);

    float o1[DB] = {};
#pragma unroll
    for (int p = 0; p < P3B; p++) {
        const float w = W3b[(e * P3B + p) * CCH + c];
#pragma unroll
        for (int d = 0; d < DB; d++) o1[d] = fmaf(w, t3b[d * P3B + p], o1[d]);
    }
#pragma unroll
    for (int p = 0; p < P2B; p++) {
        const float w = W2b[(e * P2B + p) * CCH + c];
#pragma unroll
        for (int d = 0; d < DB; d++) o1[d] = fmaf(w, t2b[d * P2B + p], o1[d]);
    }
    {
        const float w = W1b[e * CCH + c];
#pragma unroll
        for (int d = 0; d < DB; d++) o1[d] = fmaf(w, t1b[d], o1[d]);
    }

    float* op = out + b * (CCH * 4);
    op[c] = o0;
#pragma unroll
    for (int d = 0; d < DB; d++) op[CCH + c * DB + d] = o1[d];
}

extern "C" void kernel_launch(void* const* d_in, const int* in_sizes, int n_in,
                              void* d_out, int out_size, void* d_ws, size_t ws_size,
                              hipStream_t stream)
{
    // ---- order-agnostic classification by element counts (proven r5-r8) ----
    int ix = 0;
    for (int i = 1; i < n_in; i++)
        if (in_sizes[i] > in_sizes[ix]) ix = i;
    int B = in_sizes[ix] / (CCH * NELL);
    bool ok = (n_in == 14) && (B > 0) && (in_sizes[ix] == B * CCH * NELL);

    int iy = -1, E = 0;
    if (ok) {
        for (int i = 0; i < n_in; i++) {
            if (i == ix) continue;
            if (in_sizes[i] % B == 0) {
                int Ec = in_sizes[i] / B;
                if (Ec >= 2 && Ec <= 1024) {
                    if (iy < 0) { iy = i; E = Ec; } else { ok = false; }
                }
            }
        }
        if (iy < 0) ok = false;
    }

    int iU1a = -1, iU2a = -1, iU3a = -1, iU1b = -1, iU2b = -1, iU3b = -1;
    int iW1a = -1, iW1b = -1, iW2a = -1, iW2b = -1, iW3a = -1, iW3b = -1;
    if (ok) {
        for (int i = 0; i < n_in && ok; i++) {
            if (i == ix || i == iy) continue;
            int s = in_sizes[i];
            if      (s == 9 * P1A)        { if (iU1a < 0) iU1a = i; else ok = false; }
            else if (s == 81 * P2A)       { if (iU2a < 0) iU2a = i; else ok = false; }
            else if (s == 729 * P3A)      { if (iU3a < 0) iU3a = i; else ok = false; }
            else if (s == 27 * P1B)       { if (iU1b < 0) iU1b = i; else ok = false; }
            else if (s == 243 * P2B)      { if (iU2b < 0) iU2b = i; else ok = false; }
            else if (s == 2187 * P3B)     { if (iU3b < 0) iU3b = i; else ok = false; }
            else if (s == E * P1A * CCH)  { if (iW1a < 0) iW1a = i; else if (iW1b < 0) iW1b = i; else ok = false; }
            else if (s == E * P2A * CCH)  { if (iW2a < 0) iW2a = i; else ok = false; }
            else if (s == E * P2B * CCH)  { if (iW2b < 0) iW2b = i; else ok = false; }
            else if (s == E * P3A * CCH)  { if (iW3a < 0) iW3a = i; else if (iW3b < 0) iW3b = i; else ok = false; }
            else ok = false;
        }
        if (iU1a < 0 || iU2a < 0 || iU3a < 0 || iU1b < 0 || iU2b < 0 || iU3b < 0 ||
            iW1a < 0 || iW1b < 0 || iW2a < 0 || iW2b < 0 || iW3a < 0 || iW3b < 0)
            ok = false;
    }

    if (!ok) {
        // dict-order fallback
        ix = 0; iy = 1;
        B = in_sizes[0] / (CCH * NELL);
        E = (B > 0) ? in_sizes[1] / B : 1;
        iU1a = 2;  iW1a = 3;  iU2a = 4;  iW2a = 5;  iU3a = 6;  iW3a = 7;
        iU1b = 8;  iW1b = 9;  iU2b = 10; iW2b = 11; iU3b = 12; iW3b = 13;
    }

    const size_t perm_bytes = ((size_t)B * sizeof(int) + 255) & ~(size_t)255;
    const size_t tab_bytes  = (size_t)E * TTOT * CCH * 4 * sizeof(float);

    if (ws_size >= perm_bytes + tab_bytes) {
        int*   perm = (int*)d_ws;
        float* tab  = (float*)((char*)d_ws + perm_bytes);
        hipLaunchKernelGGL(sc_group, dim3(1), dim3(256), 0, stream,
                           (const float*)d_in[iy], B, E, perm);
        hipLaunchKernelGGL(sc_prep, dim3(E * TTOT), dim3(CCH), 0, stream,
                           (const float*)d_in[iU3a], (const float*)d_in[iU2a], (const float*)d_in[iU1a],
                           (const float*)d_in[iU3b], (const float*)d_in[iU2b], (const float*)d_in[iU1b],
                           (const float*)d_in[iW3a], (const float*)d_in[iW2a], (const float*)d_in[iW1a],
                           (const float*)d_in[iW3b], (const float*)d_in[iW2b], (const float*)d_in[iW1b],
                           tab);
        hipLaunchKernelGGL(sc_main2, dim3((B + GROUP - 1) / GROUP), dim3(CCH), 0, stream,
                           (const float*)d_in[ix], (const float*)d_in[iy], E, B,
                           perm, tab, (float*)d_out);
    } else if (ws_size >= tab_bytes) {
        float* tab = (float*)d_ws;
        hipLaunchKernelGGL(sc_prep, dim3(E * TTOT), dim3(CCH), 0, stream,
                           (const float*)d_in[iU3a], (const float*)d_in[iU2a], (const float*)d_in[iU1a],
                           (const float*)d_in[iU3b], (const float*)d_in[iU2b], (const float*)d_in[iU1b],
                           (const float*)d_in[iW3a], (const float*)d_in[iW2a], (const float*)d_in[iW1a],
                           (const float*)d_in[iW3b], (const float*)d_in[iW2b], (const float*)d_in[iW1b],
                           tab);
        hipLaunchKernelGGL(sc_main1, dim3(B), dim3(CCH), 0, stream,
                           (const float*)d_in[ix], (const float*)d_in[iy], E,
                           tab, (float*)d_out);
    } else {
        hipLaunchKernelGGL(sc_direct, dim3(B), dim3(CCH), 0, stream,
                           (const float*)d_in[ix], (const float*)d_in[iy], E,
                           (const float*)d_in[iU3a], (const float*)d_in[iU2a], (const float*)d_in[iU1a],
                           (const float*)d_in[iU3b], (const float*)d_in[iU2b], (const float*)d_in[iU1b],
                           (const float*)d_in[iW3a], (const float*)d_in[iW2a], (const float*)d_in[iW1a],
                           (const float*)d_in[iW3b], (const float*)d_in[iW2b], (const float*)d_in[iW1b],
                           (float*)d_out);
    }
}

// Round 10
// 59.207 us; speedup vs baseline: 8.6694x; 1.1197x over previous
//
#include <hip/hip_runtime.h>

#define NELL 9
#define CCH  128
#define DB   3
#define P3A  5
#define P2A  3
#define P1A  1
#define P3B  5
#define P2B  2
#define P1B  1
#define NT3  165
#define NT2  45
#define TTOT (NT3 + NT2 + NELL)   // 219 monomials
#define GRP  8                    // same-e rows per block (one row per s-subgroup)

// ---------------------------------------------------------------------------
// Grouping (r9-proven logic, 1024 threads): perm[slot] = batch row, sorted by
// element type e. Intra-class order nondeterministic (atomics) but final out
// is independent of slot order: each row's result depends only on its own data.
// ---------------------------------------------------------------------------
__global__ __launch_bounds__(1024)
void sc_group(const float* __restrict__ y, int B, int E, int* __restrict__ perm)
{
    __shared__ int cnt[1024];
    __shared__ int off[1024];
    for (int i = threadIdx.x; i < E; i += blockDim.x) cnt[i] = 0;
    __syncthreads();
    for (int b = threadIdx.x; b < B; b += blockDim.x) {
        int e = 0;
        for (int q = 0; q < E; q++) if (y[b * E + q] > 0.5f) e = q;
        atomicAdd(&cnt[e], 1);
    }
    __syncthreads();
    if (threadIdx.x == 0) {
        int s = 0;
        for (int e = 0; e < E; e++) { off[e] = s; s += cnt[e]; }
    }
    __syncthreads();
    for (int i = threadIdx.x; i < E; i += blockDim.x) cnt[i] = 0;
    __syncthreads();
    for (int b = threadIdx.x; b < B; b += blockDim.x) {
        int e = 0;
        for (int q = 0; q < E; q++) if (y[b * E + q] > 0.5f) e = q;
        int r = atomicAdd(&cnt[e], 1);
        perm[off[e] + r] = b;
    }
}

// ---------------------------------------------------------------------------
// Prep (r7-proven): fused coefficient table, layout [e][t][c] float4 over d:
//   tab4[(e*TTOT + t)*CCH + c] = mult_t * { sum_p U_nu[d,t,p] * W_nu[e,p,c] }
// ---------------------------------------------------------------------------
__global__ __launch_bounds__(CCH)
void sc_prep(const float* __restrict__ U3a, const float* __restrict__ U2a,
             const float* __restrict__ U1a, const float* __restrict__ U3b,
             const float* __restrict__ U2b, const float* __restrict__ U1b,
             const float* __restrict__ W3a, const float* __restrict__ W2a,
             const float* __restrict__ W1a, const float* __restrict__ W3b,
             const float* __restrict__ W2b, const float* __restrict__ W1b,
             float* __restrict__ tab)
{
    const int bt = blockIdx.x;
    const int e = bt / TTOT, t = bt % TTOT;
    const int c = threadIdx.x;

    float v[4] = {0.f, 0.f, 0.f, 0.f};

    if (t < NT3) {
        int idx = t, i = 0, j = 0, k = 0;
        bool done = false;
        for (i = 0; i < NELL && !done; i++)
            for (j = i; j < NELL && !done; j++)
                for (k = j; k < NELL; k++) {
                    if (idx == 0) { done = true; break; }
                    idx--;
                }
        i--; j--;
        const float mult = (i == k) ? 1.f : ((i == j || j == k) ? 3.f : 6.f);
        const int ijk = (i * 9 + j) * 9 + k;
        for (int p = 0; p < P3A; p++)
            v[0] += U3a[ijk * P3A + p] * W3a[(e * P3A + p) * CCH + c];
        for (int d = 0; d < DB; d++)
            for (int p = 0; p < P3B; p++)
                v[1 + d] += U3b[(d * 729 + ijk) * P3B + p] * W3b[(e * P3B + p) * CCH + c];
        for (int d = 0; d < 4; d++) v[d] *= mult;
    } else if (t < NT3 + NT2) {
        int idx = t - NT3, i = 0, j = 0;
        bool done = false;
        for (i = 0; i < NELL && !done; i++)
            for (j = i; j < NELL; j++) {
                if (idx == 0) { done = true; break; }
                idx--;
            }
        i--;
        const float mult = (i == j) ? 1.f : 2.f;
        const int ij = i * 9 + j;
        for (int p = 0; p < P2A; p++)
            v[0] += U2a[ij * P2A + p] * W2a[(e * P2A + p) * CCH + c];
        for (int d = 0; d < DB; d++)
            for (int p = 0; p < P2B; p++)
                v[1 + d] += U2b[(d * 81 + ij) * P2B + p] * W2b[(e * P2B + p) * CCH + c];
        for (int d = 0; d < 4; d++) v[d] *= mult;
    } else {
        const int i = t - NT3 - NT2;
        v[0] = U1a[i] * W1a[e * CCH + c];
        for (int d = 0; d < DB; d++)
            v[1 + d] = U1b[d * 9 + i] * W1b[e * CCH + c];
    }

    ((float4*)tab)[(size_t)bt * CCH + c] = make_float4(v[0], v[1], v[2], v[3]);
}

// ---------------------------------------------------------------------------
// Grouped main: 1024-thread block = 8 s-subgroups x 128 c-lanes. Block handles
// GRP=8 perm-adjacent rows (same e except <=E-1 boundary blocks). The 16 waves
// stream the same 448 KB table slice -> L1/L2 reuse. Body = r7 verbatim
// (bit-identical results per row). XCD-chunked swizzle keeps same-e neighbors
// on one XCD's L2.
// ---------------------------------------------------------------------------
__global__ __launch_bounds__(1024)
void sc_main8(const float* __restrict__ x, const float* __restrict__ y, int E, int B,
              const int* __restrict__ perm, const float* __restrict__ tab,
              float* __restrict__ out)
{
    const int c = threadIdx.x & (CCH - 1);
    const int s = threadIdx.x >> 7;            // wave-uniform (2 waves per s)

    int bid = blockIdx.x;
    const int nwg = gridDim.x;
    if ((nwg & 7) == 0) bid = (bid & 7) * (nwg >> 3) + (bid >> 3);  // XCD chunking

    int slot = bid * GRP + s;
    if (slot >= B) slot = B - 1;               // duplicate last row: benign identical writes
    const int b = perm[slot];

    int e = 0;                                  // wave-uniform one-hot scan
    for (int q = 0; q < E; q++) if (y[b * E + q] > 0.5f) e = q;

    float xv[NELL];
    const float* xp = x + (b * CCH + c) * NELL;
#pragma unroll
    for (int i = 0; i < NELL; i++) xv[i] = xp[i];

    const float4* cp = (const float4*)tab + (size_t)e * TTOT * CCH + c;
    float4 A = make_float4(0.f, 0.f, 0.f, 0.f);
    int t = 0;
#pragma unroll
    for (int i = 0; i < NELL; i++)
#pragma unroll
        for (int j = i; j < NELL; j++) {
            const float pij = xv[i] * xv[j];
#pragma unroll
            for (int k = j; k < NELL; k++) {
                const float m = pij * xv[k];
                const float4 w = cp[(t++) * CCH];
                A.x = fmaf(w.x, m, A.x);
                A.y = fmaf(w.y, m, A.y);
                A.z = fmaf(w.z, m, A.z);
                A.w = fmaf(w.w, m, A.w);
            }
        }
#pragma unroll
    for (int i = 0; i < NELL; i++)
#pragma unroll
        for (int j = i; j < NELL; j++) {
            const float pij = xv[i] * xv[j];
            const float4 w = cp[(t++) * CCH];
            A.x = fmaf(w.x, pij, A.x);
            A.y = fmaf(w.y, pij, A.y);
            A.z = fmaf(w.z, pij, A.z);
            A.w = fmaf(w.w, pij, A.w);
        }
#pragma unroll
    for (int i = 0; i < NELL; i++) {
        const float4 w = cp[(t++) * CCH];
        A.x = fmaf(w.x, xv[i], A.x);
        A.y = fmaf(w.y, xv[i], A.y);
        A.z = fmaf(w.z, xv[i], A.z);
        A.w = fmaf(w.w, xv[i], A.w);
    }

    float* op = out + b * (CCH * 4);           // [128 (block0) | 384 (block1, c*3+d)]
    op[c] = A.x;
    op[CCH + c * DB + 0] = A.y;
    op[CCH + c * DB + 1] = A.z;
    op[CCH + c * DB + 2] = A.w;
}

// ---------------------------------------------------------------------------
// r7 fallback main (no grouping): one row per block.
// ---------------------------------------------------------------------------
__global__ __launch_bounds__(CCH)
void sc_main1(const float* __restrict__ x, const float* __restrict__ y, int E,
              const float* __restrict__ tab, float* __restrict__ out)
{
    const int c = threadIdx.x;
    const int b = blockIdx.x;

    float xv[NELL];
    const float* xp = x + (b * CCH + c) * NELL;
#pragma unroll
    for (int i = 0; i < NELL; i++) xv[i] = xp[i];

    int e = 0;
    for (int q = 0; q < E; q++) if (y[b * E + q] > 0.5f) e = q;

    const float4* cp = (const float4*)tab + (size_t)e * TTOT * CCH + c;
    float4 A = make_float4(0.f, 0.f, 0.f, 0.f);
    int t = 0;
#pragma unroll
    for (int i = 0; i < NELL; i++)
#pragma unroll
        for (int j = i; j < NELL; j++) {
            const float pij = xv[i] * xv[j];
#pragma unroll
            for (int k = j; k < NELL; k++) {
                const float m = pij * xv[k];
                const float4 w = cp[(t++) * CCH];
                A.x = fmaf(w.x, m, A.x);
                A.y = fmaf(w.y, m, A.y);
                A.z = fmaf(w.z, m, A.z);
                A.w = fmaf(w.w, m, A.w);
            }
        }
#pragma unroll
    for (int i = 0; i < NELL; i++)
#pragma unroll
        for (int j = i; j < NELL; j++) {
            const float pij = xv[i] * xv[j];
            const float4 w = cp[(t++) * CCH];
            A.x = fmaf(w.x, pij, A.x);
            A.y = fmaf(w.y, pij, A.y);
            A.z = fmaf(w.z, pij, A.z);
            A.w = fmaf(w.w, pij, A.w);
        }
#pragma unroll
    for (int i = 0; i < NELL; i++) {
        const float4 w = cp[(t++) * CCH];
        A.x = fmaf(w.x, xv[i], A.x);
        A.y = fmaf(w.y, xv[i], A.y);
        A.z = fmaf(w.z, xv[i], A.z);
        A.w = fmaf(w.w, xv[i], A.w);
    }

    float* op = out + b * (CCH * 4);
    op[c] = A.x;
    op[CCH + c * DB + 0] = A.y;
    op[CCH + c * DB + 1] = A.z;
    op[CCH + c * DB + 2] = A.w;
}

// ---------------------------------------------------------------------------
// Last-resort fallback (no ws): r5 direct kernel.
// ---------------------------------------------------------------------------
__global__ __launch_bounds__(CCH)
void sc_direct(const float* __restrict__ x, const float* __restrict__ y, int E,
               const float* __restrict__ U3a, const float* __restrict__ U2a, const float* __restrict__ U1a,
               const float* __restrict__ U3b, const float* __restrict__ U2b, const float* __restrict__ U1b,
               const float* __restrict__ W3a, const float* __restrict__ W2a, const float* __restrict__ W1a,
               const float* __restrict__ W3b, const float* __restrict__ W2b, const float* __restrict__ W1b,
               float* __restrict__ out)
{
    const int c = threadIdx.x;
    const int b = blockIdx.x;

    float xv[NELL];
#pragma unroll
    for (int i = 0; i < NELL; i++) xv[i] = x[(b * CCH + c) * NELL + i];

    int e = 0;
    for (int q = 0; q < E; q++) if (y[b * E + q] > 0.5f) e = q;

    float t3a[P3A] = {}, t3b[DB * P3B] = {};
    float t2a[P2A] = {}, t2b[DB * P2B] = {};
    float t1a = 0.f, t1b[DB] = {};

    for (int i = 0; i < NELL; i++) {
        const float xi = xv[i];
        for (int j = 0; j < NELL; j++) {
            const float xij = xi * xv[j];
            const int ij = i * 9 + j;
#pragma unroll
            for (int p = 0; p < P2A; p++)
                t2a[p] = fmaf(U2a[ij * P2A + p], xij, t2a[p]);
#pragma unroll
            for (int d = 0; d < DB; d++)
#pragma unroll
                for (int p = 0; p < P2B; p++)
                    t2b[d * P2B + p] = fmaf(U2b[(d * 81 + ij) * P2B + p], xij, t2b[d * P2B + p]);
            for (int k = 0; k < NELL; k++) {
                const float m = xij * xv[k];
                const int ijk = ij * 9 + k;
#pragma unroll
                for (int p = 0; p < P3A; p++)
                    t3a[p] = fmaf(U3a[ijk * P3A + p], m, t3a[p]);
#pragma unroll
                for (int d = 0; d < DB; d++)
#pragma unroll
                    for (int p = 0; p < P3B; p++)
                        t3b[d * P3B + p] = fmaf(U3b[(d * 729 + ijk) * P3B + p], m, t3b[d * P3B + p]);
            }
        }
    }
#pragma unroll
    for (int i = 0; i < NELL; i++) {
        t1a = fmaf(U1a[i], xv[i], t1a);
#pragma unroll
        for (int d = 0; d < DB; d++)
            t1b[d] = fmaf(U1b[d * 9 + i], xv[i], t1b[d]);
    }

    float o0 = 0.f;
#pragma unroll
    for (int p = 0; p < P3A; p++) o0 = fmaf(W3a[(e * P3A + p) * CCH + c], t3a[p], o0);
#pragma unroll
    for (int p = 0; p < P2A; p++) o0 = fmaf(W2a[(e * P2A + p) * CCH + c], t2a[p], o0);
    o0 = fmaf(W1a[e * CCH + c], t1a, o0);

    float o1[DB] = {};
#pragma unroll
    for (int p = 0; p < P3B; p++) {
        const float w = W3b[(e * P3B + p) * CCH + c];
#pragma unroll
        for (int d = 0; d < DB; d++) o1[d] = fmaf(w, t3b[d * P3B + p], o1[d]);
    }
#pragma unroll
    for (int p = 0; p < P2B; p++) {
        const float w = W2b[(e * P2B + p) * CCH + c];
#pragma unroll
        for (int d = 0; d < DB; d++) o1[d] = fmaf(w, t2b[d * P2B + p], o1[d]);
    }
    {
        const float w = W1b[e * CCH + c];
#pragma unroll
        for (int d = 0; d < DB; d++) o1[d] = fmaf(w, t1b[d], o1[d]);
    }

    float* op = out + b * (CCH * 4);
    op[c] = o0;
#pragma unroll
    for (int d = 0; d < DB; d++) op[CCH + c * DB + d] = o1[d];
}

extern "C" void kernel_launch(void* const* d_in, const int* in_sizes, int n_in,
                              void* d_out, int out_size, void* d_ws, size_t ws_size,
                              hipStream_t stream)
{
    // ---- order-agnostic classification by element counts (proven r5-r9) ----
    int ix = 0;
    for (int i = 1; i < n_in; i++)
        if (in_sizes[i] > in_sizes[ix]) ix = i;
    int B = in_sizes[ix] / (CCH * NELL);
    bool ok = (n_in == 14) && (B > 0) && (in_sizes[ix] == B * CCH * NELL);

    int iy = -1, E = 0;
    if (ok) {
        for (int i = 0; i < n_in; i++) {
            if (i == ix) continue;
            if (in_sizes[i] % B == 0) {
                int Ec = in_sizes[i] / B;
                if (Ec >= 2 && Ec <= 1024) {
                    if (iy < 0) { iy = i; E = Ec; } else { ok = false; }
                }
            }
        }
        if (iy < 0) ok = false;
    }

    int iU1a = -1, iU2a = -1, iU3a = -1, iU1b = -1, iU2b = -1, iU3b = -1;
    int iW1a = -1, iW1b = -1, iW2a = -1, iW2b = -1, iW3a = -1, iW3b = -1;
    if (ok) {
        for (int i = 0; i < n_in && ok; i++) {
            if (i == ix || i == iy) continue;
            int s = in_sizes[i];
            if      (s == 9 * P1A)        { if (iU1a < 0) iU1a = i; else ok = false; }
            else if (s == 81 * P2A)       { if (iU2a < 0) iU2a = i; else ok = false; }
            else if (s == 729 * P3A)      { if (iU3a < 0) iU3a = i; else ok = false; }
            else if (s == 27 * P1B)       { if (iU1b < 0) iU1b = i; else ok = false; }
            else if (s == 243 * P2B)      { if (iU2b < 0) iU2b = i; else ok = false; }
            else if (s == 2187 * P3B)     { if (iU3b < 0) iU3b = i; else ok = false; }
            else if (s == E * P1A * CCH)  { if (iW1a < 0) iW1a = i; else if (iW1b < 0) iW1b = i; else ok = false; }
            else if (s == E * P2A * CCH)  { if (iW2a < 0) iW2a = i; else ok = false; }
            else if (s == E * P2B * CCH)  { if (iW2b < 0) iW2b = i; else ok = false; }
            else if (s == E * P3A * CCH)  { if (iW3a < 0) iW3a = i; else if (iW3b < 0) iW3b = i; else ok = false; }
            else ok = false;
        }
        if (iU1a < 0 || iU2a < 0 || iU3a < 0 || iU1b < 0 || iU2b < 0 || iU3b < 0 ||
            iW1a < 0 || iW1b < 0 || iW2a < 0 || iW2b < 0 || iW3a < 0 || iW3b < 0)
            ok = false;
    }

    if (!ok) {
        // dict-order fallback
        ix = 0; iy = 1;
        B = in_sizes[0] / (CCH * NELL);
        E = (B > 0) ? in_sizes[1] / B : 1;
        iU1a = 2;  iW1a = 3;  iU2a = 4;  iW2a = 5;  iU3a = 6;  iW3a = 7;
        iU1b = 8;  iW1b = 9;  iU2b = 10; iW2b = 11; iU3b = 12; iW3b = 13;
    }

    const size_t perm_bytes = ((size_t)B * sizeof(int) + 255) & ~(size_t)255;
    const size_t tab_bytes  = (size_t)E * TTOT * CCH * 4 * sizeof(float);

    if (ws_size >= perm_bytes + tab_bytes && B >= GRP) {
        int*   perm = (int*)d_ws;
        float* tab  = (float*)((char*)d_ws + perm_bytes);
        hipLaunchKernelGGL(sc_group, dim3(1), dim3(1024), 0, stream,
                           (const float*)d_in[iy], B, E, perm);
        hipLaunchKernelGGL(sc_prep, dim3(E * TTOT), dim3(CCH), 0, stream,
                           (const float*)d_in[iU3a], (const float*)d_in[iU2a], (const float*)d_in[iU1a],
                           (const float*)d_in[iU3b], (const float*)d_in[iU2b], (const float*)d_in[iU1b],
                           (const float*)d_in[iW3a], (const float*)d_in[iW2a], (const float*)d_in[iW1a],
                           (const float*)d_in[iW3b], (const float*)d_in[iW2b], (const float*)d_in[iW1b],
                           tab);
        hipLaunchKernelGGL(sc_main8, dim3((B + GRP - 1) / GRP), dim3(1024), 0, stream,
                           (const float*)d_in[ix], (const float*)d_in[iy], E, B,
                           perm, tab, (float*)d_out);
    } else if (ws_size >= tab_bytes) {
        float* tab = (float*)d_ws;
        hipLaunchKernelGGL(sc_prep, dim3(E * TTOT), dim3(CCH), 0, stream,
                           (const float*)d_in[iU3a], (const float*)d_in[iU2a], (const float*)d_in[iU1a],
                           (const float*)d_in[iU3b], (const float*)d_in[iU2b], (const float*)d_in[iU1b],
                           (const float*)d_in[iW3a], (const float*)d_in[iW2a], (const float*)d_in[iW1a],
                           (const float*)d_in[iW3b], (const float*)d_in[iW2b], (const float*)d_in[iW1b],
                           tab);
        hipLaunchKernelGGL(sc_main1, dim3(B), dim3(CCH), 0, stream,
                           (const float*)d_in[ix], (const float*)d_in[iy], E,
                           tab, (float*)d_out);
    } else {
        hipLaunchKernelGGL(sc_direct, dim3(B), dim3(CCH), 0, stream,
                           (const float*)d_in[ix], (const float*)d_in[iy], E,
                           (const float*)d_in[iU3a], (const float*)d_in[iU2a], (const float*)d_in[iU1a],
                           (const float*)d_in[iU3b], (const float*)d_in[iU2b], (const float*)d_in[iU1b],
                           (const float*)d_in[iW3a], (const float*)d_in[iW2a], (const float*)d_in[iW1a],
                           (const float*)d_in[iW3b], (const float*)d_in[iW2b], (const float*)d_in[iW1b],
                           (float*)d_out);
    }
}

// Round 11
// 58.235 us; speedup vs baseline: 8.8140x; 1.0167x over previous
//
#include <hip/hip_runtime.h>

#define NELL 9
#define CCH  128
#define DB   3
#define P3A  5
#define P2A  3
#define P1A  1
#define P3B  5
#define P2B  2
#define P1B  1
#define NT3  165
#define NT2  45
#define TTOT (NT3 + NT2 + NELL)   // 219 monomials
#define SGRP 4                    // s-subgroups per block
#define RPT  2                    // rows per thread
#define RPB  (SGRP * RPT)         // 8 rows per block

// ---------------------------------------------------------------------------
// Grouping (r9/r10-proven): perm[slot] = batch row, sorted by element type e.
// ---------------------------------------------------------------------------
__global__ __launch_bounds__(1024)
void sc_group(const float* __restrict__ y, int B, int E, int* __restrict__ perm)
{
    __shared__ int cnt[1024];
    __shared__ int off[1024];
    for (int i = threadIdx.x; i < E; i += blockDim.x) cnt[i] = 0;
    __syncthreads();
    for (int b = threadIdx.x; b < B; b += blockDim.x) {
        int e = 0;
        for (int q = 0; q < E; q++) if (y[b * E + q] > 0.5f) e = q;
        atomicAdd(&cnt[e], 1);
    }
    __syncthreads();
    if (threadIdx.x == 0) {
        int s = 0;
        for (int e = 0; e < E; e++) { off[e] = s; s += cnt[e]; }
    }
    __syncthreads();
    for (int i = threadIdx.x; i < E; i += blockDim.x) cnt[i] = 0;
    __syncthreads();
    for (int b = threadIdx.x; b < B; b += blockDim.x) {
        int e = 0;
        for (int q = 0; q < E; q++) if (y[b * E + q] > 0.5f) e = q;
        int r = atomicAdd(&cnt[e], 1);
        perm[off[e] + r] = b;
    }
}

// ---------------------------------------------------------------------------
// Prep (r7-proven): fused coefficient table, layout [e][t][c] float4 over d.
// ---------------------------------------------------------------------------
__global__ __launch_bounds__(CCH)
void sc_prep(const float* __restrict__ U3a, const float* __restrict__ U2a,
             const float* __restrict__ U1a, const float* __restrict__ U3b,
             const float* __restrict__ U2b, const float* __restrict__ U1b,
             const float* __restrict__ W3a, const float* __restrict__ W2a,
             const float* __restrict__ W1a, const float* __restrict__ W3b,
             const float* __restrict__ W2b, const float* __restrict__ W1b,
             float* __restrict__ tab)
{
    const int bt = blockIdx.x;
    const int e = bt / TTOT, t = bt % TTOT;
    const int c = threadIdx.x;

    float v[4] = {0.f, 0.f, 0.f, 0.f};

    if (t < NT3) {
        int idx = t, i = 0, j = 0, k = 0;
        bool done = false;
        for (i = 0; i < NELL && !done; i++)
            for (j = i; j < NELL && !done; j++)
                for (k = j; k < NELL; k++) {
                    if (idx == 0) { done = true; break; }
                    idx--;
                }
        i--; j--;
        const float mult = (i == k) ? 1.f : ((i == j || j == k) ? 3.f : 6.f);
        const int ijk = (i * 9 + j) * 9 + k;
        for (int p = 0; p < P3A; p++)
            v[0] += U3a[ijk * P3A + p] * W3a[(e * P3A + p) * CCH + c];
        for (int d = 0; d < DB; d++)
            for (int p = 0; p < P3B; p++)
                v[1 + d] += U3b[(d * 729 + ijk) * P3B + p] * W3b[(e * P3B + p) * CCH + c];
        for (int d = 0; d < 4; d++) v[d] *= mult;
    } else if (t < NT3 + NT2) {
        int idx = t - NT3, i = 0, j = 0;
        bool done = false;
        for (i = 0; i < NELL && !done; i++)
            for (j = i; j < NELL; j++) {
                if (idx == 0) { done = true; break; }
                idx--;
            }
        i--;
        const float mult = (i == j) ? 1.f : 2.f;
        const int ij = i * 9 + j;
        for (int p = 0; p < P2A; p++)
            v[0] += U2a[ij * P2A + p] * W2a[(e * P2A + p) * CCH + c];
        for (int d = 0; d < DB; d++)
            for (int p = 0; p < P2B; p++)
                v[1 + d] += U2b[(d * 81 + ij) * P2B + p] * W2b[(e * P2B + p) * CCH + c];
        for (int d = 0; d < 4; d++) v[d] *= mult;
    } else {
        const int i = t - NT3 - NT2;
        v[0] = U1a[i] * W1a[e * CCH + c];
        for (int d = 0; d < DB; d++)
            v[1 + d] = U1b[d * 9 + i] * W1b[e * CCH + c];
    }

    ((float4*)tab)[(size_t)bt * CCH + c] = make_float4(v[0], v[1], v[2], v[3]);
}

// ---------------------------------------------------------------------------
// Contraction core for 2 rows (r9-proven); SAME=true shares the table load.
// t-order and FMA order identical to r7 per row (bit-identical results).
// ---------------------------------------------------------------------------
template <bool SAME>
__device__ __forceinline__ void contract2(const float4* __restrict__ cp0,
                                          const float4* __restrict__ cp1,
                                          const float* xv0, const float* xv1,
                                          float4& A0, float4& A1)
{
    int t = 0;
#pragma unroll
    for (int i = 0; i < NELL; i++) {
#pragma unroll
        for (int j = i; j < NELL; j++) {
            const float p0 = xv0[i] * xv0[j];
            const float p1 = xv1[i] * xv1[j];
#pragma unroll
            for (int k = j; k < NELL; k++) {
                const float m0 = p0 * xv0[k];
                const float m1 = p1 * xv1[k];
                const float4 w0 = cp0[t * CCH];
                const float4 w1 = SAME ? w0 : cp1[t * CCH];
                A0.x = fmaf(w0.x, m0, A0.x);
                A0.y = fmaf(w0.y, m0, A0.y);
                A0.z = fmaf(w0.z, m0, A0.z);
                A0.w = fmaf(w0.w, m0, A0.w);
                A1.x = fmaf(w1.x, m1, A1.x);
                A1.y = fmaf(w1.y, m1, A1.y);
                A1.z = fmaf(w1.z, m1, A1.z);
                A1.w = fmaf(w1.w, m1, A1.w);
                t++;
            }
        }
    }
#pragma unroll
    for (int i = 0; i < NELL; i++) {
#pragma unroll
        for (int j = i; j < NELL; j++) {
            const float p0 = xv0[i] * xv0[j];
            const float p1 = xv1[i] * xv1[j];
            const float4 w0 = cp0[t * CCH];
            const float4 w1 = SAME ? w0 : cp1[t * CCH];
            A0.x = fmaf(w0.x, p0, A0.x);
            A0.y = fmaf(w0.y, p0, A0.y);
            A0.z = fmaf(w0.z, p0, A0.z);
            A0.w = fmaf(w0.w, p0, A0.w);
            A1.x = fmaf(w1.x, p1, A1.x);
            A1.y = fmaf(w1.y, p1, A1.y);
            A1.z = fmaf(w1.z, p1, A1.z);
            A1.w = fmaf(w1.w, p1, A1.w);
            t++;
        }
    }
#pragma unroll
    for (int i = 0; i < NELL; i++) {
        const float4 w0 = cp0[t * CCH];
        const float4 w1 = SAME ? w0 : cp1[t * CCH];
        A0.x = fmaf(w0.x, xv0[i], A0.x);
        A0.y = fmaf(w0.y, xv0[i], A0.y);
        A0.z = fmaf(w0.z, xv0[i], A0.z);
        A0.w = fmaf(w0.w, xv0[i], A0.w);
        A1.x = fmaf(w1.x, xv1[i], A1.x);
        A1.y = fmaf(w1.y, xv1[i], A1.y);
        A1.z = fmaf(w1.z, xv1[i], A1.z);
        A1.w = fmaf(w1.w, xv1[i], A1.w);
        t++;
    }
}

// ---------------------------------------------------------------------------
// Main: 512-thread block = 4 s-subgroups x 128 c-lanes; each thread owns
// RPT=2 perm-adjacent rows -> each table load feeds 8 FMAs; the 4 subgroups
// share the same-e slice through L1 (r10 effect). Per-row math = r7 verbatim.
// ---------------------------------------------------------------------------
__global__ __launch_bounds__(SGRP * CCH)
void sc_main_g2(const float* __restrict__ x, const float* __restrict__ y, int E, int B,
                const int* __restrict__ perm, const float* __restrict__ tab,
                float* __restrict__ out)
{
    const int c  = threadIdx.x & (CCH - 1);
    const int sg = threadIdx.x >> 7;           // 0..3, wave-uniform

    int bid = blockIdx.x;
    const int nwg = gridDim.x;
    if ((nwg & 7) == 0) bid = (bid & 7) * (nwg >> 3) + (bid >> 3);  // XCD chunking

    int slot0 = bid * RPB + sg * RPT;
    int slot1 = slot0 + 1;
    if (slot0 >= B) slot0 = B - 1;             // clamp: duplicate-identical writes, benign
    if (slot1 >= B) slot1 = B - 1;
    const int b0 = perm[slot0];
    const int b1 = perm[slot1];

    int e0 = 0, e1 = 0;                        // wave-uniform one-hot scans
    for (int q = 0; q < E; q++) if (y[b0 * E + q] > 0.5f) e0 = q;
    for (int q = 0; q < E; q++) if (y[b1 * E + q] > 0.5f) e1 = q;

    float xv0[NELL], xv1[NELL];
    const float* xp0 = x + (b0 * CCH + c) * NELL;
    const float* xp1 = x + (b1 * CCH + c) * NELL;
#pragma unroll
    for (int i = 0; i < NELL; i++) { xv0[i] = xp0[i]; xv1[i] = xp1[i]; }

    const float4* cp0 = (const float4*)tab + (size_t)e0 * TTOT * CCH + c;
    const float4* cp1 = (const float4*)tab + (size_t)e1 * TTOT * CCH + c;

    float4 A0 = make_float4(0.f, 0.f, 0.f, 0.f);
    float4 A1 = make_float4(0.f, 0.f, 0.f, 0.f);

    if (e0 == e1) contract2<true>(cp0, cp1, xv0, xv1, A0, A1);
    else          contract2<false>(cp0, cp1, xv0, xv1, A0, A1);

    float* op0 = out + b0 * (CCH * 4);         // [128 (block0) | 384 (block1, c*3+d)]
    op0[c] = A0.x;
    op0[CCH + c * DB + 0] = A0.y;
    op0[CCH + c * DB + 1] = A0.z;
    op0[CCH + c * DB + 2] = A0.w;
    float* op1 = out + b1 * (CCH * 4);
    op1[c] = A1.x;
    op1[CCH + c * DB + 0] = A1.y;
    op1[CCH + c * DB + 1] = A1.z;
    op1[CCH + c * DB + 2] = A1.w;
}

// ---------------------------------------------------------------------------
// r7 fallback main (no grouping): one row per block.
// ---------------------------------------------------------------------------
__global__ __launch_bounds__(CCH)
void sc_main1(const float* __restrict__ x, const float* __restrict__ y, int E,
              const float* __restrict__ tab, float* __restrict__ out)
{
    const int c = threadIdx.x;
    const int b = blockIdx.x;

    float xv[NELL];
    const float* xp = x + (b * CCH + c) * NELL;
#pragma unroll
    for (int i = 0; i < NELL; i++) xv[i] = xp[i];

    int e = 0;
    for (int q = 0; q < E; q++) if (y[b * E + q] > 0.5f) e = q;

    const float4* cp = (const float4*)tab + (size_t)e * TTOT * CCH + c;
    float4 A = make_float4(0.f, 0.f, 0.f, 0.f);
    int t = 0;
#pragma unroll
    for (int i = 0; i < NELL; i++)
#pragma unroll
        for (int j = i; j < NELL; j++) {
            const float pij = xv[i] * xv[j];
#pragma unroll
            for (int k = j; k < NELL; k++) {
                const float m = pij * xv[k];
                const float4 w = cp[(t++) * CCH];
                A.x = fmaf(w.x, m, A.x);
                A.y = fmaf(w.y, m, A.y);
                A.z = fmaf(w.z, m, A.z);
                A.w = fmaf(w.w, m, A.w);
            }
        }
#pragma unroll
    for (int i = 0; i < NELL; i++)
#pragma unroll
        for (int j = i; j < NELL; j++) {
            const float pij = xv[i] * xv[j];
            const float4 w = cp[(t++) * CCH];
            A.x = fmaf(w.x, pij, A.x);
            A.y = fmaf(w.y, pij, A.y);
            A.z = fmaf(w.z, pij, A.z);
            A.w = fmaf(w.w, pij, A.w);
        }
#pragma unroll
    for (int i = 0; i < NELL; i++) {
        const float4 w = cp[(t++) * CCH];
        A.x = fmaf(w.x, xv[i], A.x);
        A.y = fmaf(w.y, xv[i], A.y);
        A.z = fmaf(w.z, xv[i], A.z);
        A.w = fmaf(w.w, xv[i], A.w);
    }

    float* op = out + b * (CCH * 4);
    op[c] = A.x;
    op[CCH + c * DB + 0] = A.y;
    op[CCH + c * DB + 1] = A.z;
    op[CCH + c * DB + 2] = A.w;
}

// ---------------------------------------------------------------------------
// Last-resort fallback (no ws): r5 direct kernel.
// ---------------------------------------------------------------------------
__global__ __launch_bounds__(CCH)
void sc_direct(const float* __restrict__ x, const float* __restrict__ y, int E,
               const float* __restrict__ U3a, const float* __restrict__ U2a, const float* __restrict__ U1a,
               const float* __restrict__ U3b, const float* __restrict__ U2b, const float* __restrict__ U1b,
               const float* __restrict__ W3a, const float* __restrict__ W2a, const float* __restrict__ W1a,
               const float* __restrict__ W3b, const float* __restrict__ W2b, const float* __restrict__ W1b,
               float* __restrict__ out)
{
    const int c = threadIdx.x;
    const int b = blockIdx.x;

    float xv[NELL];
#pragma unroll
    for (int i = 0; i < NELL; i++) xv[i] = x[(b * CCH + c) * NELL + i];

    int e = 0;
    for (int q = 0; q < E; q++) if (y[b * E + q] > 0.5f) e = q;

    float t3a[P3A] = {}, t3b[DB * P3B] = {};
    float t2a[P2A] = {}, t2b[DB * P2B] = {};
    float t1a = 0.f, t1b[DB] = {};

    for (int i = 0; i < NELL; i++) {
        const float xi = xv[i];
        for (int j = 0; j < NELL; j++) {
            const float xij = xi * xv[j];
            const int ij = i * 9 + j;
#pragma unroll
            for (int p = 0; p < P2A; p++)
                t2a[p] = fmaf(U2a[ij * P2A + p], xij, t2a[p]);
#pragma unroll
            for (int d = 0; d < DB; d++)
#pragma unroll
                for (int p = 0; p < P2B; p++)
                    t2b[d * P2B + p] = fmaf(U2b[(d * 81 + ij) * P2B + p], xij, t2b[d * P2B + p]);
            for (int k = 0; k < NELL; k++) {
                const float m = xij * xv[k];
                const int ijk = ij * 9 + k;
#pragma unroll
                for (int p = 0; p < P3A; p++)
                    t3a[p] = fmaf(U3a[ijk * P3A + p], m, t3a[p]);
#pragma unroll
                for (int d = 0; d < DB; d++)
#pragma unroll
                    for (int p = 0; p < P3B; p++)
                        t3b[d * P3B + p] = fmaf(U3b[(d * 729 + ijk) * P3B + p], m, t3b[d * P3B + p]);
            }
        }
    }
#pragma unroll
    for (int i = 0; i < NELL; i++) {
        t1a = fmaf(U1a[i], xv[i], t1a);
#pragma unroll
        for (int d = 0; d < DB; d++)
            t1b[d] = fmaf(U1b[d * 9 + i], xv[i], t1b[d]);
    }

    float o0 = 0.f;
#pragma unroll
    for (int p = 0; p < P3A; p++) o0 = fmaf(W3a[(e * P3A + p) * CCH + c], t3a[p], o0);
#pragma unroll
    for (int p = 0; p < P2A; p++) o0 = fmaf(W2a[(e * P2A + p) * CCH + c], t2a[p], o0);
    o0 = fmaf(W1a[e * CCH + c], t1a, o0);

    float o1[DB] = {};
#pragma unroll
    for (int p = 0; p < P3B; p++) {
        const float w = W3b[(e * P3B + p) * CCH + c];
#pragma unroll
        for (int d = 0; d < DB; d++) o1[d] = fmaf(w, t3b[d * P3B + p], o1[d]);
    }
#pragma unroll
    for (int p = 0; p < P2B; p++) {
        const float w = W2b[(e * P2B + p) * CCH + c];
#pragma unroll
        for (int d = 0; d < DB; d++) o1[d] = fmaf(w, t2b[d * P2B + p], o1[d]);
    }
    {
        const float w = W1b[e * CCH + c];
#pragma unroll
        for (int d = 0; d < DB; d++) o1[d] = fmaf(w, t1b[d], o1[d]);
    }

    float* op = out + b * (CCH * 4);
    op[c] = o0;
#pragma unroll
    for (int d = 0; d < DB; d++) op[CCH + c * DB + d] = o1[d];
}

extern "C" void kernel_launch(void* const* d_in, const int* in_sizes, int n_in,
                              void* d_out, int out_size, void* d_ws, size_t ws_size,
                              hipStream_t stream)
{
    // ---- order-agnostic classification by element counts (proven r5-r10) ----
    int ix = 0;
    for (int i = 1; i < n_in; i++)
        if (in_sizes[i] > in_sizes[ix]) ix = i;
    int B = in_sizes[ix] / (CCH * NELL);
    bool ok = (n_in == 14) && (B > 0) && (in_sizes[ix] == B * CCH * NELL);

    int iy = -1, E = 0;
    if (ok) {
        for (int i = 0; i < n_in; i++) {
            if (i == ix) continue;
            if (in_sizes[i] % B == 0) {
                int Ec = in_sizes[i] / B;
                if (Ec >= 2 && Ec <= 1024) {
                    if (iy < 0) { iy = i; E = Ec; } else { ok = false; }
                }
            }
        }
        if (iy < 0) ok = false;
    }

    int iU1a = -1, iU2a = -1, iU3a = -1, iU1b = -1, iU2b = -1, iU3b = -1;
    int iW1a = -1, iW1b = -1, iW2a = -1, iW2b = -1, iW3a = -1, iW3b = -1;
    if (ok) {
        for (int i = 0; i < n_in && ok; i++) {
            if (i == ix || i == iy) continue;
            int s = in_sizes[i];
            if      (s == 9 * P1A)        { if (iU1a < 0) iU1a = i; else ok = false; }
            else if (s == 81 * P2A)       { if (iU2a < 0) iU2a = i; else ok = false; }
            else if (s == 729 * P3A)      { if (iU3a < 0) iU3a = i; else ok = false; }
            else if (s == 27 * P1B)       { if (iU1b < 0) iU1b = i; else ok = false; }
            else if (s == 243 * P2B)      { if (iU2b < 0) iU2b = i; else ok = false; }
            else if (s == 2187 * P3B)     { if (iU3b < 0) iU3b = i; else ok = false; }
            else if (s == E * P1A * CCH)  { if (iW1a < 0) iW1a = i; else if (iW1b < 0) iW1b = i; else ok = false; }
            else if (s == E * P2A * CCH)  { if (iW2a < 0) iW2a = i; else ok = false; }
            else if (s == E * P2B * CCH)  { if (iW2b < 0) iW2b = i; else ok = false; }
            else if (s == E * P3A * CCH)  { if (iW3a < 0) iW3a = i; else if (iW3b < 0) iW3b = i; else ok = false; }
            else ok = false;
        }
        if (iU1a < 0 || iU2a < 0 || iU3a < 0 || iU1b < 0 || iU2b < 0 || iU3b < 0 ||
            iW1a < 0 || iW1b < 0 || iW2a < 0 || iW2b < 0 || iW3a < 0 || iW3b < 0)
            ok = false;
    }

    if (!ok) {
        // dict-order fallback
        ix = 0; iy = 1;
        B = in_sizes[0] / (CCH * NELL);
        E = (B > 0) ? in_sizes[1] / B : 1;
        iU1a = 2;  iW1a = 3;  iU2a = 4;  iW2a = 5;  iU3a = 6;  iW3a = 7;
        iU1b = 8;  iW1b = 9;  iU2b = 10; iW2b = 11; iU3b = 12; iW3b = 13;
    }

    const size_t perm_bytes = ((size_t)B * sizeof(int) + 255) & ~(size_t)255;
    const size_t tab_bytes  = (size_t)E * TTOT * CCH * 4 * sizeof(float);

    if (ws_size >= perm_bytes + tab_bytes && B >= RPB) {
        int*   perm = (int*)d_ws;
        float* tab  = (float*)((char*)d_ws + perm_bytes);
        hipLaunchKernelGGL(sc_group, dim3(1), dim3(1024), 0, stream,
                           (const float*)d_in[iy], B, E, perm);
        hipLaunchKernelGGL(sc_prep, dim3(E * TTOT), dim3(CCH), 0, stream,
                           (const float*)d_in[iU3a], (const float*)d_in[iU2a], (const float*)d_in[iU1a],
                           (const float*)d_in[iU3b], (const float*)d_in[iU2b], (const float*)d_in[iU1b],
                           (const float*)d_in[iW3a], (const float*)d_in[iW2a], (const float*)d_in[iW1a],
                           (const float*)d_in[iW3b], (const float*)d_in[iW2b], (const float*)d_in[iW1b],
                           tab);
        hipLaunchKernelGGL(sc_main_g2, dim3((B + RPB - 1) / RPB), dim3(SGRP * CCH), 0, stream,
                           (const float*)d_in[ix], (const float*)d_in[iy], E, B,
                           perm, tab, (float*)d_out);
    } else if (ws_size >= tab_bytes) {
        float* tab = (float*)d_ws;
        hipLaunchKernelGGL(sc_prep, dim3(E * TTOT), dim3(CCH), 0, stream,
                           (const float*)d_in[iU3a], (const float*)d_in[iU2a], (const float*)d_in[iU1a],
                           (const float*)d_in[iU3b], (const float*)d_in[iU2b], (const float*)d_in[iU1b],
                           (const float*)d_in[iW3a], (const float*)d_in[iW2a], (const float*)d_in[iW1a],
                           (const float*)d_in[iW3b], (const float*)d_in[iW2b], (const float*)d_in[iW1b],
                           tab);
        hipLaunchKernelGGL(sc_main1, dim3(B), dim3(CCH), 0, stream,
                           (const float*)d_in[ix], (const float*)d_in[iy], E,
                           tab, (float*)d_out);
    } else {
        hipLaunchKernelGGL(sc_direct, dim3(B), dim3(CCH), 0, stream,
                           (const float*)d_in[ix], (const float*)d_in[iy], E,
                           (const float*)d_in[iU3a], (const float*)d_in[iU2a], (const float*)d_in[iU1a],
                           (const float*)d_in[iU3b], (const float*)d_in[iU2b], (const float*)d_in[iU1b],
                           (const float*)d_in[iW3a], (const float*)d_in[iW2a], (const float*)d_in[iW1a],
                           (const float*)d_in[iW3b], (const float*)d_in[iW2b], (const float*)d_in[iW1b],
                           (float*)d_out);
    }
}